// Round 3
// baseline (255.687 us; speedup 1.0000x reference)
//
#include <hip/hip_runtime.h>
#include <hip/hip_bf16.h>
#include <hip/hip_cooperative_groups.h>

namespace cg = cooperative_groups;

#define F 64          // DIN == DOUT == 64
#define BK 64         // dst nodes per bucket
#define CAP 1024      // bin stride per bucket (mean 640, sigma 25)
#define ECAP 1024     // max entries processed per bucket
#define KMAX 1600     // >= ceil(100000/64)=1563; compile-time LDS sizing for binning
#define PA_BLOCKS 512 // binning sub-grid of K1

typedef __attribute__((ext_vector_type(8))) short bf16x8;
typedef __attribute__((ext_vector_type(4))) float f32x4;

static __device__ inline short f2bf_bits(float f) {
    union { __hip_bfloat16 b; short s; } cv;
    cv.b = __float2bfloat16(f);
    return cv.s;
}

// ---------------- K1: gemm (MFMA) blocks || edge-binning blocks ----------------
__global__ void __launch_bounds__(256)
k1_kernel(const float* __restrict__ x, const float* __restrict__ W,
          __hip_bfloat16* __restrict__ h,
          const int* __restrict__ row, const int* __restrict__ col,
          int* __restrict__ bcursor, unsigned* __restrict__ bin,
          int n, int e, int ngemm, int K, int chunk) {
    __shared__ int smem[2 * KMAX];  // 12.8 KB: gemm -> Wb(short[4096]); binning -> lh|lbase
    int tid = threadIdx.x;

    if ((int)blockIdx.x < ngemm) {
        // ======== gemm: 128 rows per block (4 waves x 2 tiles) ========
        short* Wb = (short*)smem;  // [k][n] n-fastest
        for (int i = tid; i < F * F; i += 256) Wb[i] = f2bf_bits(W[i]);
        __syncthreads();
        int lane = tid & 63;
        int wv = tid >> 6;       // 0..3
        int quad = lane >> 4;    // 0..3
        int l16 = lane & 15;

        bf16x8 bfr[2][4];
#pragma unroll
        for (int ks = 0; ks < 2; ++ks)
#pragma unroll
            for (int nb = 0; nb < 4; ++nb) {
                bf16x8 f;
#pragma unroll
                for (int j = 0; j < 8; ++j)
                    f[j] = Wb[(ks * 32 + quad * 8 + j) * F + nb * 16 + l16];
                bfr[ks][nb] = f;
            }

        int blockbase = blockIdx.x * 128;
#pragma unroll
        for (int mt = 0; mt < 2; ++mt) {
            int trow = blockbase + (wv * 2 + mt) * 16;
            int ar = trow + l16;
            bf16x8 af0, af1;
            if (ar < n) {
                const float* xr = x + (size_t)ar * F + quad * 8;
                float4 v0 = ((const float4*)xr)[0];
                float4 v1 = ((const float4*)xr)[1];
                float4 v2 = ((const float4*)(xr + 32))[0];
                float4 v3 = ((const float4*)(xr + 32))[1];
                af0[0] = f2bf_bits(v0.x); af0[1] = f2bf_bits(v0.y);
                af0[2] = f2bf_bits(v0.z); af0[3] = f2bf_bits(v0.w);
                af0[4] = f2bf_bits(v1.x); af0[5] = f2bf_bits(v1.y);
                af0[6] = f2bf_bits(v1.z); af0[7] = f2bf_bits(v1.w);
                af1[0] = f2bf_bits(v2.x); af1[1] = f2bf_bits(v2.y);
                af1[2] = f2bf_bits(v2.z); af1[3] = f2bf_bits(v2.w);
                af1[4] = f2bf_bits(v3.x); af1[5] = f2bf_bits(v3.y);
                af1[6] = f2bf_bits(v3.z); af1[7] = f2bf_bits(v3.w);
            } else {
                af0 = (bf16x8)0; af1 = (bf16x8)0;
            }
            f32x4 acc[4];
#pragma unroll
            for (int nb = 0; nb < 4; ++nb) {
                acc[nb] = (f32x4)0.f;
                acc[nb] = __builtin_amdgcn_mfma_f32_16x16x32_bf16(af0, bfr[0][nb], acc[nb], 0, 0, 0);
                acc[nb] = __builtin_amdgcn_mfma_f32_16x16x32_bf16(af1, bfr[1][nb], acc[nb], 0, 0, 0);
            }
#pragma unroll
            for (int nb = 0; nb < 4; ++nb)
#pragma unroll
                for (int r = 0; r < 4; ++r) {
                    int grow = trow + quad * 4 + r;
                    if (grow < n)
                        h[(size_t)grow * F + nb * 16 + l16] = __float2bfloat16(acc[nb][r]);
                }
        }
    } else {
        // ======== passA: block-aggregated binning into fixed-stride buckets ====
        int* lh = smem;          // local histogram, then local cursor
        int* lbase = smem + KMAX;
        int pb = blockIdx.x - ngemm;
        int s = pb * chunk;
        int lim = min(s + chunk, e);
        for (int i = tid; i < K; i += 256) lh[i] = 0;
        __syncthreads();
        for (int i = s + tid; i < lim; i += 256) atomicAdd(&lh[col[i] >> 6], 1);
        __syncthreads();
        for (int i = tid; i < K; i += 256) {
            int c = lh[i];
            lbase[i] = c ? atomicAdd(&bcursor[i], c) : 0;
            lh[i] = 0;  // reuse as local cursor
        }
        __syncthreads();
        for (int i = s + tid; i < lim; i += 256) {
            int d = col[i];
            int bkt = d >> 6;
            int off = lbase[bkt] + atomicAdd(&lh[bkt], 1);
            if (off < CAP)  // statistically unreachable; guards OOB
                bin[(size_t)bkt * CAP + off] = ((unsigned)row[i] << 6) | ((unsigned)d & 63u);
        }
    }
}

// ---------------- K2 (cooperative): dinv + sort + gather fused ----------------
// Each block owns 2 buckets (b, b+nb). Phase 1: load entries to LDS, histogram,
// scan, write dinv for own nodes (this histogram previously ran TWICE - once in
// dinv_kernel, once here). grid.sync() makes all dinv visible (device-scope
// fence). Phase 2: placement fetches dinv[src] once per edge, stages (src,w) in
// LDS dst-sorted; register gather + bias + relu.
__global__ void __launch_bounds__(256, 4)
fused_kernel(const unsigned* __restrict__ bin, const int* __restrict__ bcursor,
             float* __restrict__ dinv, const __hip_bfloat16* __restrict__ h,
             const float* __restrict__ bias, float* __restrict__ out,
             int n, int K, int nb) {
    __shared__ unsigned ebuf[2][ECAP];  // raw entries          8 KB
    __shared__ uint2 sent[2][ECAP];     // dst-sorted (src, w) 16 KB
    __shared__ int lcnt[2][BK];
    __shared__ int sstart[2][BK];
    __shared__ int lcur[2][BK];
    __shared__ int sc[2][BK];
    __shared__ float sdinv[2][BK];
    int tid = threadIdx.x;
    int b0 = blockIdx.x;
    int b1 = blockIdx.x + nb;
    int cntu[2];

    // ---------- phase 1: per-bucket histogram + scan + dinv ----------
    for (int u = 0; u < 2; ++u) {
        int b = u ? b1 : b0;
        if (b >= K) { cntu[u] = 0; continue; }  // block-uniform skip
        int s = b * CAP;
        int cnt = min(bcursor[b], ECAP);
        cntu[u] = cnt;
        if (tid < BK) lcnt[u][tid] = 0;
        __syncthreads();
        for (int p = tid; p < cnt; p += 256) {
            unsigned v = bin[s + p];
            ebuf[u][p] = v;
            atomicAdd(&lcnt[u][v & 63u], 1);
        }
        __syncthreads();
        if (tid < BK) sc[u][tid] = lcnt[u][tid];
        __syncthreads();
        for (int off = 1; off < BK; off <<= 1) {
            int t = (tid < BK && tid >= off) ? sc[u][tid - off] : 0;
            __syncthreads();
            if (tid < BK) sc[u][tid] += t;
            __syncthreads();
        }
        if (tid < BK) {
            int c = lcnt[u][tid];
            int st = sc[u][tid] - c;  // exclusive
            sstart[u][tid] = st;
            lcur[u][tid] = st;
            float dv = rsqrtf((float)(c + 1));  // +1 self-loop
            sdinv[u][tid] = dv;
            int node = (b << 6) + tid;
            if (node < n) dinv[node] = dv;
        }
    }

    // ---------- grid-wide barrier: all dinv written ----------
    cg::this_grid().sync();

    // ---------- phase 2: placement (fetch w once per edge) ----------
    for (int u = 0; u < 2; ++u) {
        int b = u ? b1 : b0;
        if (b >= K) continue;
        int cnt = cntu[u];
        for (int p = tid; p < cnt; p += 256) {
            unsigned v = ebuf[u][p];
            int src = (int)(v >> 6);
            float w = dinv[src];
            int pos = atomicAdd(&lcur[u][v & 63u], 1);
            sent[u][pos] = make_uint2((unsigned)src, __float_as_uint(w));
        }
    }
    __syncthreads();

    // ---------- register gather: 32 groups of 8 lanes; 4 rounds ----------
    int g = tid >> 3, cl = tid & 7;
    const uint4* h8 = (const uint4*)h;  // [n][8] x 16 B
#pragma unroll
    for (int r = 0; r < 4; ++r) {
        int u = r >> 1;
        int b = u ? b1 : b0;
        if (b >= K) continue;
        int ln = (r & 1) * 32 + g;
        int node = (b << 6) + ln;
        if (node >= n) continue;
        float di = sdinv[u][ln];
        float a0 = 0.f, a1 = 0.f, a2 = 0.f, a3 = 0.f,
              a4 = 0.f, a5 = 0.f, a6 = 0.f, a7 = 0.f;
        {   // self-loop: di * h[node]
            uint4 hv = h8[(size_t)node * 8 + cl];
            a0 = di * __uint_as_float(hv.x << 16);
            a1 = di * __uint_as_float(hv.x & 0xffff0000u);
            a2 = di * __uint_as_float(hv.y << 16);
            a3 = di * __uint_as_float(hv.y & 0xffff0000u);
            a4 = di * __uint_as_float(hv.z << 16);
            a5 = di * __uint_as_float(hv.z & 0xffff0000u);
            a6 = di * __uint_as_float(hv.w << 16);
            a7 = di * __uint_as_float(hv.w & 0xffff0000u);
        }
        int p = sstart[u][ln];
        int pend = p + lcnt[u][ln];
        for (; p < pend; ++p) {
            uint2 ew = sent[u][p];
            float w = __uint_as_float(ew.y);
            uint4 hv = h8[(size_t)ew.x * 8 + cl];
            a0 += w * __uint_as_float(hv.x << 16);
            a1 += w * __uint_as_float(hv.x & 0xffff0000u);
            a2 += w * __uint_as_float(hv.y << 16);
            a3 += w * __uint_as_float(hv.y & 0xffff0000u);
            a4 += w * __uint_as_float(hv.z << 16);
            a5 += w * __uint_as_float(hv.z & 0xffff0000u);
            a6 += w * __uint_as_float(hv.w << 16);
            a7 += w * __uint_as_float(hv.w & 0xffff0000u);
        }
        float4 bb0 = ((const float4*)bias)[cl * 2];
        float4 bb1 = ((const float4*)bias)[cl * 2 + 1];
        float4 r0, r1;
        r0.x = di * a0 + bb0.x; r0.y = di * a1 + bb0.y;
        r0.z = di * a2 + bb0.z; r0.w = di * a3 + bb0.w;
        r1.x = di * a4 + bb1.x; r1.y = di * a5 + bb1.y;
        r1.z = di * a6 + bb1.z; r1.w = di * a7 + bb1.w;
        r0.x = r0.x > 0.f ? r0.x : 0.f; r0.y = r0.y > 0.f ? r0.y : 0.f;
        r0.z = r0.z > 0.f ? r0.z : 0.f; r0.w = r0.w > 0.f ? r0.w : 0.f;
        r1.x = r1.x > 0.f ? r1.x : 0.f; r1.y = r1.y > 0.f ? r1.y : 0.f;
        r1.z = r1.z > 0.f ? r1.z : 0.f; r1.w = r1.w > 0.f ? r1.w : 0.f;
        ((float4*)out)[(size_t)node * 16 + cl * 2] = r0;
        ((float4*)out)[(size_t)node * 16 + cl * 2 + 1] = r1;
    }
}

extern "C" void kernel_launch(void* const* d_in, const int* in_sizes, int n_in,
                              void* d_out, int out_size, void* d_ws, size_t ws_size,
                              hipStream_t stream) {
    const float* x = (const float*)d_in[0];
    const int* ei  = (const int*)d_in[1];
    const float* W = (const float*)d_in[2];
    const float* b = (const float*)d_in[3];
    float* out = (float*)d_out;

    int n = in_sizes[0] / F;   // 100000
    int e = in_sizes[1] / 2;   // 1000000
    const int* row = ei;       // source
    const int* col = ei + e;   // target
    int K = (n + BK - 1) / BK; // 1563

    // workspace layout (~19.6 MB): h | bin | dinv | bcursor
    __hip_bfloat16* h = (__hip_bfloat16*)d_ws;                    // n*F bf16   12.8 MB
    unsigned* bin = (unsigned*)((char*)d_ws + (size_t)n * F * 2); // K*CAP       6.4 MB
    float* dinv   = (float*)(bin + (size_t)KMAX * CAP);           // n           0.4 MB
    int* bcursor  = (int*)(dinv + n);                             // KMAX ints

    // 1. zero bucket cursors
    hipMemsetAsync(bcursor, 0, KMAX * sizeof(int), stream);

    // 2. K1: gemm blocks || binning blocks in one dispatch
    int ngemm = (n + 127) / 128;  // 782
    int chunk = (e + PA_BLOCKS - 1) / PA_BLOCKS;
    k1_kernel<<<ngemm + PA_BLOCKS, 256, 0, stream>>>(x, W, h, row, col, bcursor,
                                                     bin, n, e, ngemm, K, chunk);

    // 3. K2 (cooperative): dinv + sort + gather fused; 2 buckets per block.
    //    Residency: 782 blocks, 26.5 KB LDS (6/CU), launch_bounds(256,4) -> 4/CU
    //    guaranteed >= 782/256 = 3.06 needed.
    int nb = (K + 1) / 2;  // 782
    void* args[] = {(void*)&bin, (void*)&bcursor, (void*)&dinv, (void*)&h,
                    (void*)&b, (void*)&out, (void*)&n, (void*)&K, (void*)&nb};
    hipLaunchCooperativeKernel((void*)fused_kernel, dim3(nb), dim3(256), args, 0, stream);
}

// Round 5
// 135.419 us; speedup vs baseline: 1.8881x; 1.8881x over previous
//
#include <hip/hip_runtime.h>
#include <hip/hip_bf16.h>

#define F 64          // DIN == DOUT == 64
#define BK 64         // dst nodes per bucket
#define CAP 1024      // bin stride per bucket (mean 640, sigma 25 -> 15-sigma safe)
#define ECAP 1024     // max entries processed per bucket
#define KMAX 1600     // >= ceil(100000/64)=1563; compile-time LDS sizing for binning
#define PA_BLOCKS 512 // binning sub-grid of K1

typedef __attribute__((ext_vector_type(8))) short bf16x8;
typedef __attribute__((ext_vector_type(4))) float f32x4;

static __device__ inline short f2bf_bits(float f) {
    union { __hip_bfloat16 b; short s; } cv;
    cv.b = __float2bfloat16(f);
    return cv.s;
}

static __device__ inline float bf_lo(unsigned u) { return __uint_as_float(u << 16); }
static __device__ inline float bf_hi(unsigned u) { return __uint_as_float(u & 0xffff0000u); }

struct Acc8 {
    float a0, a1, a2, a3, a4, a5, a6, a7;
    __device__ inline void fma8(float wt, uint4 hv) {
        a0 += wt * bf_lo(hv.x);
        a1 += wt * bf_hi(hv.x);
        a2 += wt * bf_lo(hv.y);
        a3 += wt * bf_hi(hv.y);
        a4 += wt * bf_lo(hv.z);
        a5 += wt * bf_hi(hv.z);
        a6 += wt * bf_lo(hv.w);
        a7 += wt * bf_hi(hv.w);
    }
};

// ---------------- K1: gemm (MFMA) blocks || edge-binning blocks ----------------
__global__ void __launch_bounds__(256)
k1_kernel(const float* __restrict__ x, const float* __restrict__ W,
          __hip_bfloat16* __restrict__ h,
          const int* __restrict__ row, const int* __restrict__ col,
          int* __restrict__ bcursor, unsigned* __restrict__ bin,
          int n, int e, int ngemm, int K, int chunk) {
    __shared__ int smem[2 * KMAX];  // 12.8 KB: gemm -> Wb(short[4096]); binning -> lh|lbase
    int tid = threadIdx.x;

    if ((int)blockIdx.x < ngemm) {
        // ======== gemm: 128 rows per block (4 waves x 2 tiles) ========
        short* Wb = (short*)smem;  // [k][n] n-fastest
        for (int i = tid; i < F * F; i += 256) Wb[i] = f2bf_bits(W[i]);
        __syncthreads();
        int lane = tid & 63;
        int wv = tid >> 6;       // 0..3
        int quad = lane >> 4;    // 0..3
        int l16 = lane & 15;

        bf16x8 bfr[2][4];
#pragma unroll
        for (int ks = 0; ks < 2; ++ks)
#pragma unroll
            for (int nb = 0; nb < 4; ++nb) {
                bf16x8 f;
#pragma unroll
                for (int j = 0; j < 8; ++j)
                    f[j] = Wb[(ks * 32 + quad * 8 + j) * F + nb * 16 + l16];
                bfr[ks][nb] = f;
            }

        int blockbase = blockIdx.x * 128;
#pragma unroll
        for (int mt = 0; mt < 2; ++mt) {
            int trow = blockbase + (wv * 2 + mt) * 16;
            int ar = trow + l16;
            bf16x8 af0, af1;
            if (ar < n) {
                const float* xr = x + (size_t)ar * F + quad * 8;
                float4 v0 = ((const float4*)xr)[0];
                float4 v1 = ((const float4*)xr)[1];
                float4 v2 = ((const float4*)(xr + 32))[0];
                float4 v3 = ((const float4*)(xr + 32))[1];
                af0[0] = f2bf_bits(v0.x); af0[1] = f2bf_bits(v0.y);
                af0[2] = f2bf_bits(v0.z); af0[3] = f2bf_bits(v0.w);
                af0[4] = f2bf_bits(v1.x); af0[5] = f2bf_bits(v1.y);
                af0[6] = f2bf_bits(v1.z); af0[7] = f2bf_bits(v1.w);
                af1[0] = f2bf_bits(v2.x); af1[1] = f2bf_bits(v2.y);
                af1[2] = f2bf_bits(v2.z); af1[3] = f2bf_bits(v2.w);
                af1[4] = f2bf_bits(v3.x); af1[5] = f2bf_bits(v3.y);
                af1[6] = f2bf_bits(v3.z); af1[7] = f2bf_bits(v3.w);
            } else {
                af0 = (bf16x8)0; af1 = (bf16x8)0;
            }
            f32x4 acc[4];
#pragma unroll
            for (int nb = 0; nb < 4; ++nb) {
                acc[nb] = (f32x4)0.f;
                acc[nb] = __builtin_amdgcn_mfma_f32_16x16x32_bf16(af0, bfr[0][nb], acc[nb], 0, 0, 0);
                acc[nb] = __builtin_amdgcn_mfma_f32_16x16x32_bf16(af1, bfr[1][nb], acc[nb], 0, 0, 0);
            }
#pragma unroll
            for (int nb = 0; nb < 4; ++nb)
#pragma unroll
                for (int r = 0; r < 4; ++r) {
                    int grow = trow + quad * 4 + r;
                    if (grow < n)
                        h[(size_t)grow * F + nb * 16 + l16] = __float2bfloat16(acc[nb][r]);
                }
        }
    } else {
        // ======== passA: block-aggregated binning into fixed-stride buckets ====
        int* lh = smem;          // local histogram, then local cursor
        int* lbase = smem + KMAX;
        int pb = blockIdx.x - ngemm;
        int s = pb * chunk;
        int lim = min(s + chunk, e);
        for (int i = tid; i < K; i += 256) lh[i] = 0;
        __syncthreads();
        for (int i = s + tid; i < lim; i += 256) atomicAdd(&lh[col[i] >> 6], 1);
        __syncthreads();
        for (int i = tid; i < K; i += 256) {
            int c = lh[i];
            lbase[i] = c ? atomicAdd(&bcursor[i], c) : 0;
            lh[i] = 0;  // reuse as local cursor
        }
        __syncthreads();
        for (int i = s + tid; i < lim; i += 256) {
            int d = col[i];
            int bkt = d >> 6;
            int off = lbase[bkt] + atomicAdd(&lh[bkt], 1);
            if (off < CAP)  // statistically unreachable; guards OOB
                bin[(size_t)bkt * CAP + off] = ((unsigned)row[i] << 6) | ((unsigned)d & 63u);
        }
    }
}

// ---------------- K2a: per-bucket degree histogram -> dinv ----------------
__global__ void __launch_bounds__(256)
dinv_kernel(const unsigned* __restrict__ bin, const int* __restrict__ bcursor,
            float* __restrict__ dinv, int n) {
    __shared__ int lcnt[BK];
    int tid = threadIdx.x;
    int b = blockIdx.x;
    int s = b * CAP;
    int cnt = min(bcursor[b], ECAP);
    if (tid < BK) lcnt[tid] = 0;
    __syncthreads();
    for (int p = tid; p < cnt; p += 256) atomicAdd(&lcnt[bin[s + p] & 63u], 1);
    __syncthreads();
    if (tid < BK) {
        int node = (b << 6) + tid;
        if (node < n) dinv[node] = rsqrtf((float)(lcnt[tid] + 1));  // +1 self-loop
    }
}

// ---------------- K2b: per-bucket LDS sort + register gather + epilogue -------
// Block = bucket (64 dst nodes). Entries sorted by dst in LDS; each edge's
// weight w = dinv[src] is fetched ONCE at placement and staged packed with src
// (uint2). Gather loop is 4-wide software-pipelined: 4 independent h-row loads
// in flight per latency wait (the chain was the round-2 bottleneck).
__global__ void __launch_bounds__(256)
gather_kernel(const unsigned* __restrict__ bin, const int* __restrict__ bcursor,
              const float* __restrict__ dinv, const __hip_bfloat16* __restrict__ h,
              const float* __restrict__ bias, float* __restrict__ out, int n) {
    __shared__ unsigned ebuf[ECAP];  // raw entries          4 KB
    __shared__ uint2 sent[ECAP];     // dst-sorted (src, w)  8 KB
    __shared__ int lcnt[BK];
    __shared__ int sstart[BK];
    __shared__ int lcur[BK];
    __shared__ int sc[BK];
    __shared__ float sdinv[BK];
    int tid = threadIdx.x;
    int b = blockIdx.x;
    int base = b << 6;
    int s = b * CAP;
    int cnt = min(bcursor[b], ECAP);

    if (tid < BK) lcnt[tid] = 0;
    __syncthreads();
    // load entries to LDS + per-dst histogram
    for (int p = tid; p < cnt; p += 256) {
        unsigned u = bin[s + p];
        ebuf[p] = u;
        atomicAdd(&lcnt[u & 63u], 1);
    }
    __syncthreads();
    // inclusive scan over BK
    if (tid < BK) sc[tid] = lcnt[tid];
    __syncthreads();
    for (int off = 1; off < BK; off <<= 1) {
        int t = (tid < BK && tid >= off) ? sc[tid - off] : 0;
        __syncthreads();
        if (tid < BK) sc[tid] += t;
        __syncthreads();
    }
    if (tid < BK) {
        int c = lcnt[tid];
        int st = sc[tid] - c;  // exclusive
        sstart[tid] = st;
        lcur[tid] = st;
        sdinv[tid] = rsqrtf((float)(c + 1));  // +1 self-loop
    }
    __syncthreads();
    // place (src, w) into dst-sorted LDS list; dinv[src] fetched once per edge
    for (int p = tid; p < cnt; p += 256) {
        unsigned u = ebuf[p];
        int src = (int)(u >> 6);
        float w = dinv[src];
        int pos = atomicAdd(&lcur[u & 63u], 1);
        sent[pos] = make_uint2((unsigned)src, __float_as_uint(w));
    }
    __syncthreads();

    // register gather: 32 groups of 8 lanes; 2 rounds cover 64 nodes
    int g = tid >> 3, cl = tid & 7;
    const uint4* h8 = (const uint4*)h;  // [n][8] x 16 B
#pragma unroll
    for (int r = 0; r < 2; ++r) {
        int ln = r * 32 + g;
        int node = base + ln;
        if (node >= n) continue;
        float di = sdinv[ln];
        Acc8 ac = {0.f, 0.f, 0.f, 0.f, 0.f, 0.f, 0.f, 0.f};
        {   // self-loop: di * h[node]
            uint4 hv = h8[(size_t)node * 8 + cl];
            ac.fma8(di, hv);
        }
        int p = sstart[ln];
        int pend = p + lcnt[ln];
        // 4-wide: issue 4 LDS reads + 4 independent global h-row loads together
        for (; p + 4 <= pend; p += 4) {
            uint2 e0 = sent[p];
            uint2 e1 = sent[p + 1];
            uint2 e2 = sent[p + 2];
            uint2 e3 = sent[p + 3];
            uint4 v0 = h8[(size_t)e0.x * 8 + cl];
            uint4 v1 = h8[(size_t)e1.x * 8 + cl];
            uint4 v2 = h8[(size_t)e2.x * 8 + cl];
            uint4 v3 = h8[(size_t)e3.x * 8 + cl];
            ac.fma8(__uint_as_float(e0.y), v0);
            ac.fma8(__uint_as_float(e1.y), v1);
            ac.fma8(__uint_as_float(e2.y), v2);
            ac.fma8(__uint_as_float(e3.y), v3);
        }
        for (; p < pend; ++p) {
            uint2 ew = sent[p];
            uint4 hv = h8[(size_t)ew.x * 8 + cl];
            ac.fma8(__uint_as_float(ew.y), hv);
        }
        float4 b0 = ((const float4*)bias)[cl * 2];
        float4 b1 = ((const float4*)bias)[cl * 2 + 1];
        float4 r0, r1;
        r0.x = di * ac.a0 + b0.x; r0.y = di * ac.a1 + b0.y;
        r0.z = di * ac.a2 + b0.z; r0.w = di * ac.a3 + b0.w;
        r1.x = di * ac.a4 + b1.x; r1.y = di * ac.a5 + b1.y;
        r1.z = di * ac.a6 + b1.z; r1.w = di * ac.a7 + b1.w;
        r0.x = r0.x > 0.f ? r0.x : 0.f; r0.y = r0.y > 0.f ? r0.y : 0.f;
        r0.z = r0.z > 0.f ? r0.z : 0.f; r0.w = r0.w > 0.f ? r0.w : 0.f;
        r1.x = r1.x > 0.f ? r1.x : 0.f; r1.y = r1.y > 0.f ? r1.y : 0.f;
        r1.z = r1.z > 0.f ? r1.z : 0.f; r1.w = r1.w > 0.f ? r1.w : 0.f;
        ((float4*)out)[(size_t)node * 16 + cl * 2] = r0;
        ((float4*)out)[(size_t)node * 16 + cl * 2 + 1] = r1;
    }
}

extern "C" void kernel_launch(void* const* d_in, const int* in_sizes, int n_in,
                              void* d_out, int out_size, void* d_ws, size_t ws_size,
                              hipStream_t stream) {
    const float* x = (const float*)d_in[0];
    const int* ei  = (const int*)d_in[1];
    const float* W = (const float*)d_in[2];
    const float* b = (const float*)d_in[3];
    float* out = (float*)d_out;

    int n = in_sizes[0] / F;   // 100000
    int e = in_sizes[1] / 2;   // 1000000
    const int* row = ei;       // source
    const int* col = ei + e;   // target
    int K = (n + BK - 1) / BK; // 1563

    // workspace layout (~19.6 MB): h | bin | dinv | bcursor
    __hip_bfloat16* h = (__hip_bfloat16*)d_ws;                    // n*F bf16   12.8 MB
    unsigned* bin = (unsigned*)((char*)d_ws + (size_t)n * F * 2); // K*CAP       6.4 MB
    float* dinv   = (float*)(bin + (size_t)KMAX * CAP);           // n           0.4 MB
    int* bcursor  = (int*)(dinv + n);                             // KMAX ints

    // 1. zero bucket cursors
    (void)hipMemsetAsync(bcursor, 0, KMAX * sizeof(int), stream);

    // 2. K1: gemm blocks || binning blocks in one dispatch
    int ngemm = (n + 127) / 128;  // 782
    int chunk = (e + PA_BLOCKS - 1) / PA_BLOCKS;
    k1_kernel<<<ngemm + PA_BLOCKS, 256, 0, stream>>>(x, W, h, row, col, bcursor,
                                                     bin, n, e, ngemm, K, chunk);

    // 3. K2a: per-bucket degree histogram -> dinv
    dinv_kernel<<<K, 256, 0, stream>>>(bin, bcursor, dinv, n);

    // 4. K2b: per-bucket LDS sort + 4-wide pipelined register gather
    gather_kernel<<<K, 256, 0, stream>>>(bin, bcursor, dinv, h, b, out, n);
}